// Round 4
// baseline (167.551 us; speedup 1.0000x reference)
//
#include <hip/hip_runtime.h>

#define NSEG 8192           // faces per set
#define NPTS (3 * NSEG)     // 24576 unified points [S | T | R]
#define NSUP 96             // 256-point super-tiles (32 per segment)
#define NXB  192            // 2 blocks (128 i-rows each) per super-tile
#define NYG  7              // y-groups: g=0..6 -> Y=7g..7g+6 (uniform, 49 total)

typedef short bf16x8 __attribute__((ext_vector_type(8)));   // 8 bf16 (4 VGPRs)
typedef float f32x16 __attribute__((ext_vector_type(16)));  // 16 fp32 acc
typedef unsigned short u16;

__device__ __forceinline__ u16 f2bf(float x) {              // RNE f32 -> bf16 bits
    unsigned u = __builtin_bit_cast(unsigned, x);
    return (u16)((u + 0x7FFFu + ((u >> 16) & 1u)) >> 16);
}
__device__ __forceinline__ float bf2f(u16 h) {
    unsigned u = ((unsigned)h) << 16;
    return __builtin_bit_cast(float, u);
}

__device__ __forceinline__ void compute_point(
    int seg, int f,
    const float* __restrict__ sv, const int* __restrict__ si,
    const float* __restrict__ tv, const int* __restrict__ ti,
    const float* __restrict__ rn, const float* __restrict__ rc,
    float& cx, float& cy, float& cz, float& nx, float& ny, float& nz)
{
    if (seg == 2) {
        nx = rn[3*f];   ny = rn[3*f+1]; nz = rn[3*f+2];
        cx = rc[3*f];   cy = rc[3*f+1]; cz = rc[3*f+2];
    } else {
        const float* v  = (seg == 0) ? sv : tv;
        const int*   nd = (seg == 0) ? si : ti;
        int i0 = nd[3*f], i1 = nd[3*f+1], i2 = nd[3*f+2];
        float ax = v[3*i0], ay = v[3*i0+1], az = v[3*i0+2];
        float bx = v[3*i1], by = v[3*i1+1], bz = v[3*i1+2];
        float gx = v[3*i2], gy = v[3*i2+1], gz = v[3*i2+2];
        float ux = ax-bx, uy = ay-by, uz = az-bz;
        float wx = gx-bx, wy = gy-by, wz = gz-bz;
        nx = 0.5f*(uy*wz - uz*wy);
        ny = 0.5f*(uz*wx - ux*wz);
        nz = 0.5f*(ux*wy - uy*wx);
        cx = (ax+bx+gx)*(1.0f/3.0f);
        cy = (ay+by+gy)*(1.0f/3.0f);
        cz = (az+bz+gz)*(1.0f/3.0f);
    }
}

// Feature rows (K=16 bf16), hi/lo split: t = A_t . B_t = 1+|ci-cj|^2 (~1e-3 abs err).
// Interleaved records: A-side point = {at[16], an[16]} (64 B), B-side = {bt[16], bn[16]}.
__global__ void setup_feats(const float* __restrict__ sv, const int* __restrict__ si,
                            const float* __restrict__ tv, const int* __restrict__ ti,
                            const float* __restrict__ rn, const float* __restrict__ rc,
                            u16* __restrict__ ws, float* __restrict__ out) {
    int p = blockIdx.x * 256 + threadIdx.x;
    if (p == 0) out[0] = 0.0f;          // d_out poisoned 0xAA before every launch
    if (p >= NPTS) return;
    int seg = p >> 13, f = p & (NSEG - 1);
    float cx, cy, cz, nx, ny, nz;
    compute_point(seg, f, sv, si, tv, ti, rn, rc, cx, cy, cz, nx, ny, nz);

    const u16 ONE = 0x3F80;
    float s = cx*cx + cy*cy + cz*cz;
    u16 chx = f2bf(cx), chy = f2bf(cy), chz = f2bf(cz);
    u16 clx = f2bf(cx - bf2f(chx)), cly = f2bf(cy - bf2f(chy)), clz = f2bf(cz - bf2f(chz));
    u16 sh  = f2bf(s);
    u16 sl  = f2bf(s - bf2f(sh));
    u16 m2hx = f2bf(-2.0f*bf2f(chx)), m2hy = f2bf(-2.0f*bf2f(chy)), m2hz = f2bf(-2.0f*bf2f(chz));
    u16 m2lx = f2bf(-2.0f*bf2f(clx)), m2ly = f2bf(-2.0f*bf2f(cly)), m2lz = f2bf(-2.0f*bf2f(clz));
    u16 nhx = f2bf(nx), nhy = f2bf(ny), nhz = f2bf(nz);
    u16 nlx = f2bf(nx - bf2f(nhx)), nly = f2bf(ny - bf2f(nhy)), nlz = f2bf(nz - bf2f(nhz));

    u16 at[16] = {chx,chy,chz, clx,cly,clz, chx,chy,chz, sh, sl, ONE, ONE, ONE, 0, 0};
    u16 bt[16] = {m2hx,m2hy,m2hz, m2hx,m2hy,m2hz, m2lx,m2ly,m2lz, ONE, ONE, sh, sl, ONE, 0, 0};
    u16 an[16] = {nhx,nhy,nhz, nlx,nly,nlz, nhx,nhy,nhz, 0,0,0,0,0,0,0};
    u16 bn[16] = {nhx,nhy,nhz, nhx,nhy,nhz, nlx,nly,nlz, 0,0,0,0,0,0,0};

    bf16x8* A8 = (bf16x8*)ws;            // A-record: frags [at0 at1 an0 an1] per point
    bf16x8* B8 = A8 + (size_t)NPTS*4;    // B-record: frags [bt0 bt1 bn0 bn1] per point
    bf16x8 v0, v1, v2, v3;
    #pragma unroll
    for (int k = 0; k < 8; ++k) { v0[k] = (short)at[k]; v1[k] = (short)at[k+8];
                                  v2[k] = (short)an[k]; v3[k] = (short)an[k+8]; }
    A8[(size_t)p*4+0] = v0; A8[(size_t)p*4+1] = v1; A8[(size_t)p*4+2] = v2; A8[(size_t)p*4+3] = v3;
    #pragma unroll
    for (int k = 0; k < 8; ++k) { v0[k] = (short)bt[k]; v1[k] = (short)bt[k+8];
                                  v2[k] = (short)bn[k]; v3[k] = (short)bn[k+8]; }
    B8[(size_t)p*4+0] = v0; B8[(size_t)p*4+1] = v1; B8[(size_t)p*4+2] = v2; B8[(size_t)p*4+3] = v3;
}

// Symmetric-pair kernel. R13: inner math byte-for-byte R9/R12 (VGPR=32 sweet
// spot — R10/R11 deeper pipelines spilled). Changes:
//  (1) NYG=7: 49 y's = 7 uniform groups of 7 -> grid 192x7=1344 blocks, all
//      blocks identical work (R12's 10-group split had a 4/5-work group and
//      1920 blocks vs ~1280-1536 resident => ~1.25 generations; occupancy cap
//      is AGPR+VGPR (~48 acc regs) at 5-6 waves/SIMD, NOT 8).
//  (2) jt loop FULLY unrolled: depth-1 prefetch rotation becomes SSA renaming
//      (kills 16 v_mov/tile under the old partial unroll) and address adds fold.
//  (3) branchless block-uniform weight (no runtime-indexed array).
// Accumulation order over (y,jt,gq) identical -> bitwise-same energy.
// Wrapped map over 256-pt super-tiles: (I,J) = (X, (X+Y)%96); mult = 2 except
// Y==0 (diagonal, once) and Y==48 (hit from both ends) -> 96+96+96*47*2 = 96^2. ✓
__launch_bounds__(256, 3)
__global__ void energy_mfma(const u16* __restrict__ ws, float* __restrict__ out) {
    const int tid  = threadIdx.x;
    const int lane = tid & 63, wid = tid >> 6;
    const int half = lane >> 5, r32 = lane & 31;

    const int bx = blockIdx.x;                // 0..191
    const int X  = bx >> 1;                   // super-tile row 0..95
    const int g  = blockIdx.y;                // 0..6
    const int y0 = 7*g;                       // uniform: 7 y's per block
    const int gi = X >> 5;                    // 32 super-tiles per segment

    const bf16x8* A8 = (const bf16x8*)ws;
    const bf16x8* B8 = A8 + (size_t)NPTS*4;

    // one persistent 32-row i-tile per wave: rows X*256 + (bx&1)*128 + wid*32 + r32
    const int pi = X*256 + (bx & 1)*128 + wid*32 + r32;
    const bf16x8 at = A8[pi*4 + half];
    const bf16x8 an = A8[pi*4 + 2 + half];

    f32x16 Z;
    #pragma unroll
    for (int k = 0; k < 16; ++k) Z[k] = 0.0f;

    const int lofs = r32*4 + half;            // per-lane frag offset within a j-tile

    float acc = 0.0f;
    for (int yy = 0; yy < 7; ++yy) {
        const int y = y0 + yy;
        int J = X + y; if (J >= NSUP) J -= NSUP;

        // branchless block-uniform weight (scalar): Wt[gi][jg] * mult
        const int jg = J >> 5;
        float base_w;
        if (gi == jg)                 base_w = (gi == 2) ? 2.0f : 1.8f;
        else if (gi == 2 || jg == 2)  base_w = -1.0f;
        else                          base_w = -0.8f;
        const float w = base_w * ((y == 0 || y == 48) ? 1.0f : 2.0f);

        // int32 B addressing: point stride 4 frags; j-tile stride 128; super-tile 1024
        const int base = J*1024 + lofs;

        // depth-1 prefetch, FULL unroll -> rotation is pure SSA renaming
        bf16x8 cbt = B8[base];
        bf16x8 cbn = B8[base + 2];

        float ts0 = 0.0f, ts1 = 0.0f;
        #pragma unroll
        for (int jt = 0; jt < 8; ++jt) {
            bf16x8 nbt, nbn;
            if (jt < 7) {                      // compile-time guard (full unroll)
                nbt = B8[base + (jt + 1)*128];
                nbn = B8[base + (jt + 1)*128 + 2];
            }

            f32x16 ct = __builtin_amdgcn_mfma_f32_32x32x16_bf16(at, cbt, Z, 0, 0, 0);
            f32x16 cn = __builtin_amdgcn_mfma_f32_32x32x16_bf16(an, cbn, Z, 0, 0, 0);

            // batched rcp: one v_rcp per 4 pairs; two independent partial chains
            #pragma unroll
            for (int gq = 0; gq < 4; ++gq) {
                float t0 = ct[4*gq+0], t1 = ct[4*gq+1], t2 = ct[4*gq+2], t3 = ct[4*gq+3];
                float q0 = t0*t0, q1 = t1*t1, q2 = t2*t2, q3 = t3*t3;
                float s01 = q0*q1, s23 = q2*q3;
                float r   = __builtin_amdgcn_rcpf(s01*s23);
                float u   = __builtin_fmaf(cn[4*gq+1], q0, cn[4*gq+0]*q1);
                float v   = __builtin_fmaf(cn[4*gq+3], q2, cn[4*gq+2]*q3);
                float num = __builtin_fmaf(v, s01, u*s23);
                if (gq & 1) ts1 = __builtin_fmaf(num, r, ts1);
                else        ts0 = __builtin_fmaf(num, r, ts0);
            }

            if (jt < 7) { cbt = nbt; cbn = nbn; }   // SSA rename, no movs
        }
        acc = __builtin_fmaf(w, ts0 + ts1, acc);
    }

    // wave shuffle reduce -> 4 partials -> one atomic per block
    for (int off = 32; off; off >>= 1) acc += __shfl_down(acc, off, 64);
    __shared__ float partial[4];
    if ((tid & 63) == 0) partial[wid] = acc;
    __syncthreads();
    if (tid == 0)
        atomicAdd(out, (partial[0] + partial[1]) + (partial[2] + partial[3]));
}

extern "C" void kernel_launch(void* const* d_in, const int* in_sizes, int n_in,
                              void* d_out, int out_size, void* d_ws, size_t ws_size,
                              hipStream_t stream) {
    const float* sv = (const float*)d_in[0];
    const int*   si = (const int*)d_in[1];
    const float* tv = (const float*)d_in[2];
    const int*   ti = (const int*)d_in[3];
    const float* rn = (const float*)d_in[4];
    const float* rc = (const float*)d_in[5];
    float* out = (float*)d_out;
    u16*   ws  = (u16*)d_ws;                      // 2 x 24576 x 64 B = 3 MB features

    setup_feats<<<NPTS/256, 256, 0, stream>>>(sv, si, tv, ti, rn, rc, ws, out);
    dim3 grid(NXB, NYG);                          // 192 x 7 = 1344 uniform blocks
    energy_mfma<<<grid, 256, 0, stream>>>(ws, out);
}

// Round 5
// 119.791 us; speedup vs baseline: 1.3987x; 1.3987x over previous
//
#include <hip/hip_runtime.h>

#define NSEG 8192           // faces per set
#define NPTS (3 * NSEG)     // 24576 unified points [S | T | R]
#define NSUP 96             // 256-point super-tiles (32 per segment)
#define NXB  192            // 2 blocks (128 i-rows each) per super-tile
#define NYG  7              // y-groups: g=0..6 -> Y=7g..7g+6 (uniform, 49 total)

typedef short bf16x8 __attribute__((ext_vector_type(8)));   // 8 bf16 (4 VGPRs)
typedef float f32x16 __attribute__((ext_vector_type(16)));  // 16 fp32 acc
typedef unsigned short u16;

__device__ __forceinline__ u16 f2bf(float x) {              // RNE f32 -> bf16 bits
    unsigned u = __builtin_bit_cast(unsigned, x);
    return (u16)((u + 0x7FFFu + ((u >> 16) & 1u)) >> 16);
}
__device__ __forceinline__ float bf2f(u16 h) {
    unsigned u = ((unsigned)h) << 16;
    return __builtin_bit_cast(float, u);
}

__device__ __forceinline__ void compute_point(
    int seg, int f,
    const float* __restrict__ sv, const int* __restrict__ si,
    const float* __restrict__ tv, const int* __restrict__ ti,
    const float* __restrict__ rn, const float* __restrict__ rc,
    float& cx, float& cy, float& cz, float& nx, float& ny, float& nz)
{
    if (seg == 2) {
        nx = rn[3*f];   ny = rn[3*f+1]; nz = rn[3*f+2];
        cx = rc[3*f];   cy = rc[3*f+1]; cz = rc[3*f+2];
    } else {
        const float* v  = (seg == 0) ? sv : tv;
        const int*   nd = (seg == 0) ? si : ti;
        int i0 = nd[3*f], i1 = nd[3*f+1], i2 = nd[3*f+2];
        float ax = v[3*i0], ay = v[3*i0+1], az = v[3*i0+2];
        float bx = v[3*i1], by = v[3*i1+1], bz = v[3*i1+2];
        float gx = v[3*i2], gy = v[3*i2+1], gz = v[3*i2+2];
        float ux = ax-bx, uy = ay-by, uz = az-bz;
        float wx = gx-bx, wy = gy-by, wz = gz-bz;
        nx = 0.5f*(uy*wz - uz*wy);
        ny = 0.5f*(uz*wx - ux*wz);
        nz = 0.5f*(ux*wy - uy*wx);
        cx = (ax+bx+gx)*(1.0f/3.0f);
        cy = (ay+by+gy)*(1.0f/3.0f);
        cz = (az+bz+gz)*(1.0f/3.0f);
    }
}

// Feature rows (K=16 bf16), hi/lo split: t = A_t . B_t = 1+|ci-cj|^2 (~1e-3 abs err).
// Interleaved records: A-side point = {at[16], an[16]} (64 B), B-side = {bt[16], bn[16]}.
__global__ void setup_feats(const float* __restrict__ sv, const int* __restrict__ si,
                            const float* __restrict__ tv, const int* __restrict__ ti,
                            const float* __restrict__ rn, const float* __restrict__ rc,
                            u16* __restrict__ ws, float* __restrict__ out) {
    int p = blockIdx.x * 256 + threadIdx.x;
    if (p == 0) out[0] = 0.0f;          // d_out poisoned 0xAA before every launch
    if (p >= NPTS) return;
    int seg = p >> 13, f = p & (NSEG - 1);
    float cx, cy, cz, nx, ny, nz;
    compute_point(seg, f, sv, si, tv, ti, rn, rc, cx, cy, cz, nx, ny, nz);

    const u16 ONE = 0x3F80;
    float s = cx*cx + cy*cy + cz*cz;
    u16 chx = f2bf(cx), chy = f2bf(cy), chz = f2bf(cz);
    u16 clx = f2bf(cx - bf2f(chx)), cly = f2bf(cy - bf2f(chy)), clz = f2bf(cz - bf2f(chz));
    u16 sh  = f2bf(s);
    u16 sl  = f2bf(s - bf2f(sh));
    u16 m2hx = f2bf(-2.0f*bf2f(chx)), m2hy = f2bf(-2.0f*bf2f(chy)), m2hz = f2bf(-2.0f*bf2f(chz));
    u16 m2lx = f2bf(-2.0f*bf2f(clx)), m2ly = f2bf(-2.0f*bf2f(cly)), m2lz = f2bf(-2.0f*bf2f(clz));
    u16 nhx = f2bf(nx), nhy = f2bf(ny), nhz = f2bf(nz);
    u16 nlx = f2bf(nx - bf2f(nhx)), nly = f2bf(ny - bf2f(nhy)), nlz = f2bf(nz - bf2f(nhz));

    u16 at[16] = {chx,chy,chz, clx,cly,clz, chx,chy,chz, sh, sl, ONE, ONE, ONE, 0, 0};
    u16 bt[16] = {m2hx,m2hy,m2hz, m2hx,m2hy,m2hz, m2lx,m2ly,m2lz, ONE, ONE, sh, sl, ONE, 0, 0};
    u16 an[16] = {nhx,nhy,nhz, nlx,nly,nlz, nhx,nhy,nhz, 0,0,0,0,0,0,0};
    u16 bn[16] = {nhx,nhy,nhz, nhx,nhy,nhz, nlx,nly,nlz, 0,0,0,0,0,0,0};

    bf16x8* A8 = (bf16x8*)ws;            // A-record: frags [at0 at1 an0 an1] per point
    bf16x8* B8 = A8 + (size_t)NPTS*4;    // B-record: frags [bt0 bt1 bn0 bn1] per point
    bf16x8 v0, v1, v2, v3;
    #pragma unroll
    for (int k = 0; k < 8; ++k) { v0[k] = (short)at[k]; v1[k] = (short)at[k+8];
                                  v2[k] = (short)an[k]; v3[k] = (short)an[k+8]; }
    A8[(size_t)p*4+0] = v0; A8[(size_t)p*4+1] = v1; A8[(size_t)p*4+2] = v2; A8[(size_t)p*4+3] = v3;
    #pragma unroll
    for (int k = 0; k < 8; ++k) { v0[k] = (short)bt[k]; v1[k] = (short)bt[k+8];
                                  v2[k] = (short)bn[k]; v3[k] = (short)bn[k+8]; }
    B8[(size_t)p*4+0] = v0; B8[(size_t)p*4+1] = v1; B8[(size_t)p*4+2] = v2; B8[(size_t)p*4+3] = v3;
}

// Symmetric-pair kernel. R14 = R12 inner loop BYTE-FOR-BYTE (the only proven
// non-spilling schedule: VGPR=32, partial unroll 2, depth-1 rotation, runtime
// Wt[] weight lookup — R10/R11/R13 all re-triggered the spill cliff via wider
// live ranges: dbl-acc / depth-2 / full unroll -> WRITE_SIZE 392/237/252 MB)
// + NYG=7 uniform geometry: 49 y's = 7 groups x 7 -> grid 192x7 = 1344 blocks,
// all identical work, <= ~1536 resident (unified-file cap: 32 VGPR + ~48 acc
// AGPR = 6 waves/SIMD) -> ONE dispatch generation vs R12's ~1.25.
// #pragma unroll 1 on the y-loop forbids the unroll that spilled R13.
// Accumulation order over (y,jt,gq) identical -> bitwise-same energy.
// Wrapped map over 256-pt super-tiles: (I,J) = (X, (X+Y)%96); mult = 2 except
// Y==0 (diagonal, once) and Y==48 (hit from both ends) -> 96+96+96*47*2 = 96^2. ✓
__launch_bounds__(256, 3)
__global__ void energy_mfma(const u16* __restrict__ ws, float* __restrict__ out) {
    const int tid  = threadIdx.x;
    const int lane = tid & 63, wid = tid >> 6;
    const int half = lane >> 5, r32 = lane & 31;

    const int bx = blockIdx.x;                // 0..191
    const int X  = bx >> 1;                   // super-tile row 0..95
    const int g  = blockIdx.y;                // 0..6
    const int y0 = 7*g;                       // uniform: 7 y's per block
    const int ycnt = 7;
    const int gi = X >> 5;                    // 32 super-tiles per segment

    const float Wt[9] = {1.8f, -0.8f, -1.0f,
                        -0.8f,  1.8f, -1.0f,
                        -1.0f, -1.0f,  2.0f};

    const bf16x8* A8 = (const bf16x8*)ws;
    const bf16x8* B8 = A8 + (size_t)NPTS*4;

    // one persistent 32-row i-tile per wave: rows X*256 + (bx&1)*128 + wid*32 + r32
    const int pi = X*256 + (bx & 1)*128 + wid*32 + r32;
    const bf16x8 at = A8[pi*4 + half];
    const bf16x8 an = A8[pi*4 + 2 + half];

    f32x16 Z;
    #pragma unroll
    for (int k = 0; k < 16; ++k) Z[k] = 0.0f;

    const int lofs = r32*4 + half;            // per-lane frag offset within a j-tile

    float acc = 0.0f;
    #pragma unroll 1
    for (int yy = 0; yy < ycnt; ++yy) {
        const int y = y0 + yy;
        int J = X + y; if (J >= NSUP) J -= NSUP;
        const float mult = (y == 0 || y == 48) ? 1.0f : 2.0f;
        const float w = Wt[gi*3 + (J >> 5)] * mult;   // block-uniform per y

        // int32 B addressing: point stride 4 frags; j-tile stride 128; super-tile 1024
        const int base = J*1024 + lofs;

        // prefetch rotation in named registers
        bf16x8 btf = B8[base];
        bf16x8 bnf = B8[base + 2];

        float ts0 = 0.0f, ts1 = 0.0f;
        #pragma unroll 2
        for (int jt = 0; jt < 8; ++jt) {
            int nofs = base + ((jt < 7) ? (jt + 1) : jt) * 128;  // clamped redundant last
            bf16x8 nbt = B8[nofs];
            bf16x8 nbn = B8[nofs + 2];

            f32x16 ct = __builtin_amdgcn_mfma_f32_32x32x16_bf16(at, btf, Z, 0, 0, 0);
            f32x16 cn = __builtin_amdgcn_mfma_f32_32x32x16_bf16(an, bnf, Z, 0, 0, 0);

            // batched rcp: one v_rcp per 4 pairs; two independent partial chains
            #pragma unroll
            for (int gq = 0; gq < 4; ++gq) {
                float t0 = ct[4*gq+0], t1 = ct[4*gq+1], t2 = ct[4*gq+2], t3 = ct[4*gq+3];
                float q0 = t0*t0, q1 = t1*t1, q2 = t2*t2, q3 = t3*t3;
                float s01 = q0*q1, s23 = q2*q3;
                float r   = __builtin_amdgcn_rcpf(s01*s23);
                float u   = __builtin_fmaf(cn[4*gq+1], q0, cn[4*gq+0]*q1);
                float v   = __builtin_fmaf(cn[4*gq+3], q2, cn[4*gq+2]*q3);
                float num = __builtin_fmaf(v, s01, u*s23);
                if (gq & 1) ts1 = __builtin_fmaf(num, r, ts1);
                else        ts0 = __builtin_fmaf(num, r, ts0);
            }

            btf = nbt; bnf = nbn;
        }
        acc = __builtin_fmaf(w, ts0 + ts1, acc);
    }

    // wave shuffle reduce -> 4 partials -> one atomic per block
    for (int off = 32; off; off >>= 1) acc += __shfl_down(acc, off, 64);
    __shared__ float partial[4];
    if ((tid & 63) == 0) partial[wid] = acc;
    __syncthreads();
    if (tid == 0)
        atomicAdd(out, (partial[0] + partial[1]) + (partial[2] + partial[3]));
}

extern "C" void kernel_launch(void* const* d_in, const int* in_sizes, int n_in,
                              void* d_out, int out_size, void* d_ws, size_t ws_size,
                              hipStream_t stream) {
    const float* sv = (const float*)d_in[0];
    const int*   si = (const int*)d_in[1];
    const float* tv = (const float*)d_in[2];
    const int*   ti = (const int*)d_in[3];
    const float* rn = (const float*)d_in[4];
    const float* rc = (const float*)d_in[5];
    float* out = (float*)d_out;
    u16*   ws  = (u16*)d_ws;                      // 2 x 24576 x 64 B = 3 MB features

    setup_feats<<<NPTS/256, 256, 0, stream>>>(sv, si, tv, ti, rn, rc, ws, out);
    dim3 grid(NXB, NYG);                          // 192 x 7 = 1344 uniform blocks
    energy_mfma<<<grid, 256, 0, stream>>>(ws, out);
}

// Round 7
// 114.355 us; speedup vs baseline: 1.4652x; 1.0475x over previous
//
#include <hip/hip_runtime.h>

#define NSEG 8192           // faces per set
#define NPTS (3 * NSEG)     // 24576 unified points [S | T | R]
#define NSUP 96             // 256-point super-tiles (32 per segment)
#define NXB  192            // 2 blocks (128 i-rows each) per super-tile
#define NYG  10             // y-groups: g<9 -> Y=5g..5g+4; g==9 -> Y=45..48

typedef short bf16x8 __attribute__((ext_vector_type(8)));   // 8 bf16 (4 VGPRs)
typedef float f32x16 __attribute__((ext_vector_type(16)));  // 16 fp32 acc
typedef unsigned short u16;

__device__ __forceinline__ u16 f2bf(float x) {              // RNE f32 -> bf16 bits
    unsigned u = __builtin_bit_cast(unsigned, x);
    return (u16)((u + 0x7FFFu + ((u >> 16) & 1u)) >> 16);
}
__device__ __forceinline__ float bf2f(u16 h) {
    unsigned u = ((unsigned)h) << 16;
    return __builtin_bit_cast(float, u);
}

__device__ __forceinline__ void compute_point(
    int seg, int f,
    const float* __restrict__ sv, const int* __restrict__ si,
    const float* __restrict__ tv, const int* __restrict__ ti,
    const float* __restrict__ rn, const float* __restrict__ rc,
    float& cx, float& cy, float& cz, float& nx, float& ny, float& nz)
{
    if (seg == 2) {
        nx = rn[3*f];   ny = rn[3*f+1]; nz = rn[3*f+2];
        cx = rc[3*f];   cy = rc[3*f+1]; cz = rc[3*f+2];
    } else {
        const float* v  = (seg == 0) ? sv : tv;
        const int*   nd = (seg == 0) ? si : ti;
        int i0 = nd[3*f], i1 = nd[3*f+1], i2 = nd[3*f+2];
        float ax = v[3*i0], ay = v[3*i0+1], az = v[3*i0+2];
        float bx = v[3*i1], by = v[3*i1+1], bz = v[3*i1+2];
        float gx = v[3*i2], gy = v[3*i2+1], gz = v[3*i2+2];
        float ux = ax-bx, uy = ay-by, uz = az-bz;
        float wx = gx-bx, wy = gy-by, wz = gz-bz;
        nx = 0.5f*(uy*wz - uz*wy);
        ny = 0.5f*(uz*wx - ux*wz);
        nz = 0.5f*(ux*wy - uy*wx);
        cx = (ax+bx+gx)*(1.0f/3.0f);
        cy = (ay+by+gy)*(1.0f/3.0f);
        cz = (az+bz+gz)*(1.0f/3.0f);
    }
}

// Feature rows (K=16 bf16), hi/lo split: t = A_t . B_t = 1+|ci-cj|^2 (~1e-3 abs err).
// Interleaved records: A-side point = {at[16], an[16]} (64 B), B-side = {bt[16], bn[16]}.
__global__ void setup_feats(const float* __restrict__ sv, const int* __restrict__ si,
                            const float* __restrict__ tv, const int* __restrict__ ti,
                            const float* __restrict__ rn, const float* __restrict__ rc,
                            u16* __restrict__ ws, float* __restrict__ out) {
    int p = blockIdx.x * 256 + threadIdx.x;
    if (p == 0) out[0] = 0.0f;          // d_out poisoned 0xAA before every launch
    if (p >= NPTS) return;
    int seg = p >> 13, f = p & (NSEG - 1);
    float cx, cy, cz, nx, ny, nz;
    compute_point(seg, f, sv, si, tv, ti, rn, rc, cx, cy, cz, nx, ny, nz);

    const u16 ONE = 0x3F80;
    float s = cx*cx + cy*cy + cz*cz;
    u16 chx = f2bf(cx), chy = f2bf(cy), chz = f2bf(cz);
    u16 clx = f2bf(cx - bf2f(chx)), cly = f2bf(cy - bf2f(chy)), clz = f2bf(cz - bf2f(chz));
    u16 sh  = f2bf(s);
    u16 sl  = f2bf(s - bf2f(sh));
    u16 m2hx = f2bf(-2.0f*bf2f(chx)), m2hy = f2bf(-2.0f*bf2f(chy)), m2hz = f2bf(-2.0f*bf2f(chz));
    u16 m2lx = f2bf(-2.0f*bf2f(clx)), m2ly = f2bf(-2.0f*bf2f(cly)), m2lz = f2bf(-2.0f*bf2f(clz));
    u16 nhx = f2bf(nx), nhy = f2bf(ny), nhz = f2bf(nz);
    u16 nlx = f2bf(nx - bf2f(nhx)), nly = f2bf(ny - bf2f(nhy)), nlz = f2bf(nz - bf2f(nhz));

    u16 at[16] = {chx,chy,chz, clx,cly,clz, chx,chy,chz, sh, sl, ONE, ONE, ONE, 0, 0};
    u16 bt[16] = {m2hx,m2hy,m2hz, m2hx,m2hy,m2hz, m2lx,m2ly,m2lz, ONE, ONE, sh, sl, ONE, 0, 0};
    u16 an[16] = {nhx,nhy,nhz, nlx,nly,nlz, nhx,nhy,nhz, 0,0,0,0,0,0,0};
    u16 bn[16] = {nhx,nhy,nhz, nhx,nhy,nhz, nlx,nly,nlz, 0,0,0,0,0,0,0};

    bf16x8* A8 = (bf16x8*)ws;            // A-record: frags [at0 at1 an0 an1] per point
    bf16x8* B8 = A8 + (size_t)NPTS*4;    // B-record: frags [bt0 bt1 bn0 bn1] per point
    bf16x8 v0, v1, v2, v3;
    #pragma unroll
    for (int k = 0; k < 8; ++k) { v0[k] = (short)at[k]; v1[k] = (short)at[k+8];
                                  v2[k] = (short)an[k]; v3[k] = (short)an[k+8]; }
    A8[(size_t)p*4+0] = v0; A8[(size_t)p*4+1] = v1; A8[(size_t)p*4+2] = v2; A8[(size_t)p*4+3] = v3;
    #pragma unroll
    for (int k = 0; k < 8; ++k) { v0[k] = (short)bt[k]; v1[k] = (short)bt[k+8];
                                  v2[k] = (short)bn[k]; v3[k] = (short)bn[k+8]; }
    B8[(size_t)p*4+0] = v0; B8[(size_t)p*4+1] = v1; B8[(size_t)p*4+2] = v2; B8[(size_t)p*4+3] = v3;
}

// Symmetric-pair kernel. R15 (resubmit after infra failure): depth-2 prefetch
// pipeline (R11 inner loop, bitwise-correct there) with the REGISTER CEILING
// LIFTED: __launch_bounds__(256,2) -> unified VGPR+AGPR budget ~256/wave
// instead of ~170. Post-mortem insight: R10/R11/R13 "spills at VGPR=84" were
// the (256,3) bound forcing unified-file overflow to scratch, not true
// pressure. Depth-2 covers the ~250-cyc L2 load latency that depth-1's
// ~200-cyc EPI gap left exposed (R9/R12/R14 plateau at VALUBusy 55-60%).
// Geometry = R12's measured-best: NYG=10 (1920 blocks; R14's 1344 regressed).
// Accumulation order over (y,jt,gq) identical to R9-R14 -> bitwise-same energy.
// Wrapped map over 256-pt super-tiles: (I,J) = (X, (X+Y)%96); mult = 2 except
// Y==0 (diagonal, once) and Y==48 (hit from both ends) -> 96+96+96*47*2 = 96^2. ✓
__launch_bounds__(256, 2)
__global__ void energy_mfma(const u16* __restrict__ ws, float* __restrict__ out) {
    const int tid  = threadIdx.x;
    const int lane = tid & 63, wid = tid >> 6;
    const int half = lane >> 5, r32 = lane & 31;

    const int bx = blockIdx.x;                // 0..191
    const int X  = bx >> 1;                   // super-tile row 0..95
    const int g  = blockIdx.y;                // 0..9
    const int y0  = (g < 9) ? 5*g : 45;
    const int ycnt = (g < 9) ? 5 : 4;
    const int gi = X >> 5;                    // 32 super-tiles per segment

    const bf16x8* A8 = (const bf16x8*)ws;
    const bf16x8* B8 = A8 + (size_t)NPTS*4;

    // one persistent 32-row i-tile per wave: rows X*256 + (bx&1)*128 + wid*32 + r32
    const int pi = X*256 + (bx & 1)*128 + wid*32 + r32;
    const bf16x8 at = A8[pi*4 + half];
    const bf16x8 an = A8[pi*4 + 2 + half];

    f32x16 Z;
    #pragma unroll
    for (int k = 0; k < 16; ++k) Z[k] = 0.0f;

    const int lofs = r32*4 + half;            // per-lane frag offset within a j-tile

    // per-y addressing + weight (block-uniform), branchless (no indexed array)
    auto yinfo = [&](int y, int& vo, float& w) {
        int J = X + y; if (J >= NSUP) J -= NSUP;
        int jg = J >> 5;
        float base_w;
        if (gi == jg)                 base_w = (gi == 2) ? 2.0f : 1.8f;
        else if (gi == 2 || jg == 2)  base_w = -1.0f;
        else                          base_w = -0.8f;
        const float mult = (y == 0 || y == 48) ? 1.0f : 2.0f;
        w = base_w * mult;
        vo = J*1024 + lofs;                   // frag index: stride 4/point, 128/j-tile
    };

    float acc = 0.0f;
    int vo; float w;
    yinfo(y0, vo, w);

    // prologue: tiles 0 and 1 of the first y in flight (depth-2 pipeline)
    bf16x8 bt0 = B8[vo],       bn0 = B8[vo + 2];
    bf16x8 bt1 = B8[vo + 128], bn1 = B8[vo + 130];

    #pragma unroll 1
    for (int yy = 0; yy < ycnt; ++yy) {
        // next-y addressing (clamped on the last y -> harmless redundant loads)
        int von; float wn;
        yinfo((yy + 1 < ycnt) ? (y0 + yy + 1) : (y0 + yy), von, wn);

        float ts0 = 0.0f, ts1 = 0.0f;
        #pragma unroll 2
        for (int jt = 0; jt < 8; ++jt) {
            // prefetch tile jt+2 (tiles 6/7 fetch next-y tiles 0/1)
            const int pofs = (jt < 6) ? (vo + (jt + 2)*128) : (von + (jt - 6)*128);
            bf16x8 pt = B8[pofs];
            bf16x8 pn = B8[pofs + 2];

            f32x16 ct = __builtin_amdgcn_mfma_f32_32x32x16_bf16(at, bt0, Z, 0, 0, 0);
            f32x16 cn = __builtin_amdgcn_mfma_f32_32x32x16_bf16(an, bn0, Z, 0, 0, 0);

            // batched rcp: one v_rcp per 4 pairs; two independent partial chains
            #pragma unroll
            for (int gq = 0; gq < 4; ++gq) {
                float t0 = ct[4*gq+0], t1 = ct[4*gq+1], t2 = ct[4*gq+2], t3 = ct[4*gq+3];
                float q0 = t0*t0, q1 = t1*t1, q2 = t2*t2, q3 = t3*t3;
                float s01 = q0*q1, s23 = q2*q3;
                float r   = __builtin_amdgcn_rcpf(s01*s23);
                float u   = __builtin_fmaf(cn[4*gq+1], q0, cn[4*gq+0]*q1);
                float v   = __builtin_fmaf(cn[4*gq+3], q2, cn[4*gq+2]*q3);
                float num = __builtin_fmaf(v, s01, u*s23);
                if (gq & 1) ts1 = __builtin_fmaf(num, r, ts1);
                else        ts0 = __builtin_fmaf(num, r, ts0);
            }

            // rotate pipeline (named registers; SSA renaming under unroll 2)
            bt0 = bt1; bn0 = bn1;
            bt1 = pt;  bn1 = pn;
        }
        acc = __builtin_fmaf(w, ts0 + ts1, acc);
        vo = von; w = wn;
    }

    // wave shuffle reduce -> 4 partials -> one atomic per block
    for (int off = 32; off; off >>= 1) acc += __shfl_down(acc, off, 64);
    __shared__ float partial[4];
    if ((tid & 63) == 0) partial[wid] = acc;
    __syncthreads();
    if (tid == 0)
        atomicAdd(out, (partial[0] + partial[1]) + (partial[2] + partial[3]));
}

extern "C" void kernel_launch(void* const* d_in, const int* in_sizes, int n_in,
                              void* d_out, int out_size, void* d_ws, size_t ws_size,
                              hipStream_t stream) {
    const float* sv = (const float*)d_in[0];
    const int*   si = (const int*)d_in[1];
    const float* tv = (const float*)d_in[2];
    const int*   ti = (const int*)d_in[3];
    const float* rn = (const float*)d_in[4];
    const float* rc = (const float*)d_in[5];
    float* out = (float*)d_out;
    u16*   ws  = (u16*)d_ws;                      // 2 x 24576 x 64 B = 3 MB features

    setup_feats<<<NPTS/256, 256, 0, stream>>>(sv, si, tv, ti, rn, rc, ws, out);
    dim3 grid(NXB, NYG);                          // 192 x 10 = 1920 blocks of 256
    energy_mfma<<<grid, 256, 0, stream>>>(ws, out);
}

// Round 8
// 114.330 us; speedup vs baseline: 1.4655x; 1.0002x over previous
//
#include <hip/hip_runtime.h>

#define NSEG 8192           // faces per set
#define NPTS (3 * NSEG)     // 24576 unified points [S | T | R]
#define NSUP 96             // 256-point super-tiles (32 per segment)
#define NXB  96             // ONE block per super-tile row (R16: 2 i-tiles/wave)
#define NYG  10             // y-groups: g<9 -> Y=5g..5g+4; g==9 -> Y=45..48

typedef short bf16x8 __attribute__((ext_vector_type(8)));   // 8 bf16 (4 VGPRs)
typedef float f32x16 __attribute__((ext_vector_type(16)));  // 16 fp32 acc
typedef unsigned short u16;

__device__ __forceinline__ u16 f2bf(float x) {              // RNE f32 -> bf16 bits
    unsigned u = __builtin_bit_cast(unsigned, x);
    return (u16)((u + 0x7FFFu + ((u >> 16) & 1u)) >> 16);
}
__device__ __forceinline__ float bf2f(u16 h) {
    unsigned u = ((unsigned)h) << 16;
    return __builtin_bit_cast(float, u);
}

__device__ __forceinline__ void compute_point(
    int seg, int f,
    const float* __restrict__ sv, const int* __restrict__ si,
    const float* __restrict__ tv, const int* __restrict__ ti,
    const float* __restrict__ rn, const float* __restrict__ rc,
    float& cx, float& cy, float& cz, float& nx, float& ny, float& nz)
{
    if (seg == 2) {
        nx = rn[3*f];   ny = rn[3*f+1]; nz = rn[3*f+2];
        cx = rc[3*f];   cy = rc[3*f+1]; cz = rc[3*f+2];
    } else {
        const float* v  = (seg == 0) ? sv : tv;
        const int*   nd = (seg == 0) ? si : ti;
        int i0 = nd[3*f], i1 = nd[3*f+1], i2 = nd[3*f+2];
        float ax = v[3*i0], ay = v[3*i0+1], az = v[3*i0+2];
        float bx = v[3*i1], by = v[3*i1+1], bz = v[3*i1+2];
        float gx = v[3*i2], gy = v[3*i2+1], gz = v[3*i2+2];
        float ux = ax-bx, uy = ay-by, uz = az-bz;
        float wx = gx-bx, wy = gy-by, wz = gz-bz;
        nx = 0.5f*(uy*wz - uz*wy);
        ny = 0.5f*(uz*wx - ux*wz);
        nz = 0.5f*(ux*wy - uy*wx);
        cx = (ax+bx+gx)*(1.0f/3.0f);
        cy = (ay+by+gy)*(1.0f/3.0f);
        cz = (az+bz+gz)*(1.0f/3.0f);
    }
}

// Feature rows (K=16 bf16), hi/lo split: t = A_t . B_t = 1+|ci-cj|^2 (~1e-3 abs err).
// Interleaved records: A-side point = {at[16], an[16]} (64 B), B-side = {bt[16], bn[16]}.
__global__ void setup_feats(const float* __restrict__ sv, const int* __restrict__ si,
                            const float* __restrict__ tv, const int* __restrict__ ti,
                            const float* __restrict__ rn, const float* __restrict__ rc,
                            u16* __restrict__ ws, float* __restrict__ out) {
    int p = blockIdx.x * 256 + threadIdx.x;
    if (p == 0) out[0] = 0.0f;          // d_out poisoned 0xAA before every launch
    if (p >= NPTS) return;
    int seg = p >> 13, f = p & (NSEG - 1);
    float cx, cy, cz, nx, ny, nz;
    compute_point(seg, f, sv, si, tv, ti, rn, rc, cx, cy, cz, nx, ny, nz);

    const u16 ONE = 0x3F80;
    float s = cx*cx + cy*cy + cz*cz;
    u16 chx = f2bf(cx), chy = f2bf(cy), chz = f2bf(cz);
    u16 clx = f2bf(cx - bf2f(chx)), cly = f2bf(cy - bf2f(chy)), clz = f2bf(cz - bf2f(chz));
    u16 sh  = f2bf(s);
    u16 sl  = f2bf(s - bf2f(sh));
    u16 m2hx = f2bf(-2.0f*bf2f(chx)), m2hy = f2bf(-2.0f*bf2f(chy)), m2hz = f2bf(-2.0f*bf2f(chz));
    u16 m2lx = f2bf(-2.0f*bf2f(clx)), m2ly = f2bf(-2.0f*bf2f(cly)), m2lz = f2bf(-2.0f*bf2f(clz));
    u16 nhx = f2bf(nx), nhy = f2bf(ny), nhz = f2bf(nz);
    u16 nlx = f2bf(nx - bf2f(nhx)), nly = f2bf(ny - bf2f(nhy)), nlz = f2bf(nz - bf2f(nhz));

    u16 at[16] = {chx,chy,chz, clx,cly,clz, chx,chy,chz, sh, sl, ONE, ONE, ONE, 0, 0};
    u16 bt[16] = {m2hx,m2hy,m2hz, m2hx,m2hy,m2hz, m2lx,m2ly,m2lz, ONE, ONE, sh, sl, ONE, 0, 0};
    u16 an[16] = {nhx,nhy,nhz, nlx,nly,nlz, nhx,nhy,nhz, 0,0,0,0,0,0,0};
    u16 bn[16] = {nhx,nhy,nhz, nhx,nhy,nhz, nlx,nly,nlz, 0,0,0,0,0,0,0};

    bf16x8* A8 = (bf16x8*)ws;            // A-record: frags [at0 at1 an0 an1] per point
    bf16x8* B8 = A8 + (size_t)NPTS*4;    // B-record: frags [bt0 bt1 bn0 bn1] per point
    bf16x8 v0, v1, v2, v3;
    #pragma unroll
    for (int k = 0; k < 8; ++k) { v0[k] = (short)at[k]; v1[k] = (short)at[k+8];
                                  v2[k] = (short)an[k]; v3[k] = (short)an[k+8]; }
    A8[(size_t)p*4+0] = v0; A8[(size_t)p*4+1] = v1; A8[(size_t)p*4+2] = v2; A8[(size_t)p*4+3] = v3;
    #pragma unroll
    for (int k = 0; k < 8; ++k) { v0[k] = (short)bt[k]; v1[k] = (short)bt[k+8];
                                  v2[k] = (short)bn[k]; v3[k] = (short)bn[k+8]; }
    B8[(size_t)p*4+0] = v0; B8[(size_t)p*4+1] = v1; B8[(size_t)p*4+2] = v2; B8[(size_t)p*4+3] = v3;
}

// Symmetric-pair kernel. R16: TWO i-tiles per wave (rows pi and pi+128 of the
// super-tile) run against every loaded B fragment -> per-MFMA-pair overhead
// (B loads, addressing, rotation, loop control: the non-EPI ~60% of the VALU
// stream) halves, and NXB drops to 96 -> grid 96x10 = 960 blocks < ~1024-1280
// resident capacity -> ONE dispatch generation (the tail NYG tuning never
// fixed). Depth-2 prefetch + (256,2) bound retained from R15 (proven VGPR=40,
// zero spill there; gate = WRITE_SIZE stays ~60 B).
// Per-i-tile EPI accumulation order unchanged; the two i-tiles' partials join
// acc sequentially (grouping change only at the already-commutative atomic).
// Wrapped map over 256-pt super-tiles: (I,J) = (X, (X+Y)%96); mult = 2 except
// Y==0 (diagonal, once) and Y==48 (hit from both ends) -> 96+96+96*47*2 = 96^2. ✓
__launch_bounds__(256, 2)
__global__ void energy_mfma(const u16* __restrict__ ws, float* __restrict__ out) {
    const int tid  = threadIdx.x;
    const int lane = tid & 63, wid = tid >> 6;
    const int half = lane >> 5, r32 = lane & 31;

    const int X  = blockIdx.x;                // 0..95 (super-tile row)
    const int g  = blockIdx.y;                // 0..9
    const int y0  = (g < 9) ? 5*g : 45;
    const int ycnt = (g < 9) ? 5 : 4;
    const int gi = X >> 5;                    // 32 super-tiles per segment

    const bf16x8* A8 = (const bf16x8*)ws;
    const bf16x8* B8 = A8 + (size_t)NPTS*4;

    // two persistent 32-row i-tiles per wave: rows pi and pi+128
    const int pi = X*256 + wid*32 + r32;
    const bf16x8 at0 = A8[pi*4 + half];
    const bf16x8 an0 = A8[pi*4 + 2 + half];
    const bf16x8 at1 = A8[pi*4 + 512 + half];        // +128 points * 4 frags
    const bf16x8 an1 = A8[pi*4 + 514 + half];

    f32x16 Z;
    #pragma unroll
    for (int k = 0; k < 16; ++k) Z[k] = 0.0f;

    const int lofs = r32*4 + half;            // per-lane frag offset within a j-tile

    // per-y addressing + weight (block-uniform), branchless (no indexed array)
    auto yinfo = [&](int y, int& vo, float& w) {
        int J = X + y; if (J >= NSUP) J -= NSUP;
        int jg = J >> 5;
        float base_w;
        if (gi == jg)                 base_w = (gi == 2) ? 2.0f : 1.8f;
        else if (gi == 2 || jg == 2)  base_w = -1.0f;
        else                          base_w = -0.8f;
        const float mult = (y == 0 || y == 48) ? 1.0f : 2.0f;
        w = base_w * mult;
        vo = J*1024 + lofs;                   // frag index: stride 4/point, 128/j-tile
    };

    // batched rcp: one v_rcp per 4 pairs; two independent partial chains
#define EPI(CT, CN, TS0, TS1) do {                                            \
        _Pragma("unroll")                                                     \
        for (int gq = 0; gq < 4; ++gq) {                                      \
            float t0 = CT[4*gq+0], t1 = CT[4*gq+1];                           \
            float t2 = CT[4*gq+2], t3 = CT[4*gq+3];                           \
            float q0 = t0*t0, q1 = t1*t1, q2 = t2*t2, q3 = t3*t3;             \
            float s01 = q0*q1, s23 = q2*q3;                                   \
            float r   = __builtin_amdgcn_rcpf(s01*s23);                       \
            float u   = __builtin_fmaf(CN[4*gq+1], q0, CN[4*gq+0]*q1);        \
            float v   = __builtin_fmaf(CN[4*gq+3], q2, CN[4*gq+2]*q3);        \
            float num = __builtin_fmaf(v, s01, u*s23);                        \
            if (gq & 1) TS1 = __builtin_fmaf(num, r, TS1);                    \
            else        TS0 = __builtin_fmaf(num, r, TS0);                    \
        }                                                                     \
    } while (0)

    float acc = 0.0f;
    int vo; float w;
    yinfo(y0, vo, w);

    // prologue: tiles 0 and 1 of the first y in flight (depth-2 pipeline)
    bf16x8 bt0 = B8[vo],       bn0 = B8[vo + 2];
    bf16x8 bt1 = B8[vo + 128], bn1 = B8[vo + 130];

    #pragma unroll 1
    for (int yy = 0; yy < ycnt; ++yy) {
        // next-y addressing (clamped on the last y -> harmless redundant loads)
        int von; float wn;
        yinfo((yy + 1 < ycnt) ? (y0 + yy + 1) : (y0 + yy), von, wn);

        float tsA0 = 0.0f, tsA1 = 0.0f;       // i-tile 0 partials
        float tsB0 = 0.0f, tsB1 = 0.0f;       // i-tile 1 partials
        #pragma unroll 2
        for (int jt = 0; jt < 8; ++jt) {
            // prefetch tile jt+2 (tiles 6/7 fetch next-y tiles 0/1)
            const int pofs = (jt < 6) ? (vo + (jt + 2)*128) : (von + (jt - 6)*128);
            bf16x8 pt = B8[pofs];
            bf16x8 pn = B8[pofs + 2];

            f32x16 ct, cn;
            ct = __builtin_amdgcn_mfma_f32_32x32x16_bf16(at0, bt0, Z, 0, 0, 0);
            cn = __builtin_amdgcn_mfma_f32_32x32x16_bf16(an0, bn0, Z, 0, 0, 0);
            EPI(ct, cn, tsA0, tsA1);
            ct = __builtin_amdgcn_mfma_f32_32x32x16_bf16(at1, bt0, Z, 0, 0, 0);
            cn = __builtin_amdgcn_mfma_f32_32x32x16_bf16(an1, bn0, Z, 0, 0, 0);
            EPI(ct, cn, tsB0, tsB1);

            // rotate pipeline (named registers; SSA renaming under unroll 2)
            bt0 = bt1; bn0 = bn1;
            bt1 = pt;  bn1 = pn;
        }
        acc = __builtin_fmaf(w, tsA0 + tsA1, acc);
        acc = __builtin_fmaf(w, tsB0 + tsB1, acc);
        vo = von; w = wn;
    }
#undef EPI

    // wave shuffle reduce -> 4 partials -> one atomic per block
    for (int off = 32; off; off >>= 1) acc += __shfl_down(acc, off, 64);
    __shared__ float partial[4];
    if ((tid & 63) == 0) partial[wid] = acc;
    __syncthreads();
    if (tid == 0)
        atomicAdd(out, (partial[0] + partial[1]) + (partial[2] + partial[3]));
}

extern "C" void kernel_launch(void* const* d_in, const int* in_sizes, int n_in,
                              void* d_out, int out_size, void* d_ws, size_t ws_size,
                              hipStream_t stream) {
    const float* sv = (const float*)d_in[0];
    const int*   si = (const int*)d_in[1];
    const float* tv = (const float*)d_in[2];
    const int*   ti = (const int*)d_in[3];
    const float* rn = (const float*)d_in[4];
    const float* rc = (const float*)d_in[5];
    float* out = (float*)d_out;
    u16*   ws  = (u16*)d_ws;                      // 2 x 24576 x 64 B = 3 MB features

    setup_feats<<<NPTS/256, 256, 0, stream>>>(sv, si, tv, ti, rn, rc, ws, out);
    dim3 grid(NXB, NYG);                          // 96 x 10 = 960 blocks of 256
    energy_mfma<<<grid, 256, 0, stream>>>(ws, out);
}

// Round 9
// 112.312 us; speedup vs baseline: 1.4918x; 1.0180x over previous
//
#include <hip/hip_runtime.h>

#define NSEG 8192           // faces per set
#define NPTS (3 * NSEG)     // 24576 unified points [S | T | R]
#define NSUP 96             // 256-point super-tiles (32 per segment)
#define NXB  96             // ONE block per super-tile row (2 i-tiles/wave)
#define NYG  25             // y-groups: g<24 -> Y=2g,2g+1; g==24 -> Y=48

typedef short bf16x8 __attribute__((ext_vector_type(8)));   // 8 bf16 (4 VGPRs)
typedef float f32x16 __attribute__((ext_vector_type(16)));  // 16 fp32 acc
typedef unsigned short u16;

__device__ __forceinline__ u16 f2bf(float x) {              // RNE f32 -> bf16 bits
    unsigned u = __builtin_bit_cast(unsigned, x);
    return (u16)((u + 0x7FFFu + ((u >> 16) & 1u)) >> 16);
}
__device__ __forceinline__ float bf2f(u16 h) {
    unsigned u = ((unsigned)h) << 16;
    return __builtin_bit_cast(float, u);
}

__device__ __forceinline__ void compute_point(
    int seg, int f,
    const float* __restrict__ sv, const int* __restrict__ si,
    const float* __restrict__ tv, const int* __restrict__ ti,
    const float* __restrict__ rn, const float* __restrict__ rc,
    float& cx, float& cy, float& cz, float& nx, float& ny, float& nz)
{
    if (seg == 2) {
        nx = rn[3*f];   ny = rn[3*f+1]; nz = rn[3*f+2];
        cx = rc[3*f];   cy = rc[3*f+1]; cz = rc[3*f+2];
    } else {
        const float* v  = (seg == 0) ? sv : tv;
        const int*   nd = (seg == 0) ? si : ti;
        int i0 = nd[3*f], i1 = nd[3*f+1], i2 = nd[3*f+2];
        float ax = v[3*i0], ay = v[3*i0+1], az = v[3*i0+2];
        float bx = v[3*i1], by = v[3*i1+1], bz = v[3*i1+2];
        float gx = v[3*i2], gy = v[3*i2+1], gz = v[3*i2+2];
        float ux = ax-bx, uy = ay-by, uz = az-bz;
        float wx = gx-bx, wy = gy-by, wz = gz-bz;
        nx = 0.5f*(uy*wz - uz*wy);
        ny = 0.5f*(uz*wx - ux*wz);
        nz = 0.5f*(ux*wy - uy*wx);
        cx = (ax+bx+gx)*(1.0f/3.0f);
        cy = (ay+by+gy)*(1.0f/3.0f);
        cz = (az+bz+gz)*(1.0f/3.0f);
    }
}

// Feature rows (K=16 bf16), hi/lo split: t = A_t . B_t = 1+|ci-cj|^2 (~1e-3 abs err).
// Interleaved records: A-side point = {at[16], an[16]} (64 B), B-side = {bt[16], bn[16]}.
__global__ void setup_feats(const float* __restrict__ sv, const int* __restrict__ si,
                            const float* __restrict__ tv, const int* __restrict__ ti,
                            const float* __restrict__ rn, const float* __restrict__ rc,
                            u16* __restrict__ ws, float* __restrict__ out) {
    int p = blockIdx.x * 256 + threadIdx.x;
    if (p == 0) out[0] = 0.0f;          // d_out poisoned 0xAA before every launch
    if (p >= NPTS) return;
    int seg = p >> 13, f = p & (NSEG - 1);
    float cx, cy, cz, nx, ny, nz;
    compute_point(seg, f, sv, si, tv, ti, rn, rc, cx, cy, cz, nx, ny, nz);

    const u16 ONE = 0x3F80;
    float s = cx*cx + cy*cy + cz*cz;
    u16 chx = f2bf(cx), chy = f2bf(cy), chz = f2bf(cz);
    u16 clx = f2bf(cx - bf2f(chx)), cly = f2bf(cy - bf2f(chy)), clz = f2bf(cz - bf2f(chz));
    u16 sh  = f2bf(s);
    u16 sl  = f2bf(s - bf2f(sh));
    u16 m2hx = f2bf(-2.0f*bf2f(chx)), m2hy = f2bf(-2.0f*bf2f(chy)), m2hz = f2bf(-2.0f*bf2f(chz));
    u16 m2lx = f2bf(-2.0f*bf2f(clx)), m2ly = f2bf(-2.0f*bf2f(cly)), m2lz = f2bf(-2.0f*bf2f(clz));
    u16 nhx = f2bf(nx), nhy = f2bf(ny), nhz = f2bf(nz);
    u16 nlx = f2bf(nx - bf2f(nhx)), nly = f2bf(ny - bf2f(nhy)), nlz = f2bf(nz - bf2f(nhz));

    u16 at[16] = {chx,chy,chz, clx,cly,clz, chx,chy,chz, sh, sl, ONE, ONE, ONE, 0, 0};
    u16 bt[16] = {m2hx,m2hy,m2hz, m2hx,m2hy,m2hz, m2lx,m2ly,m2lz, ONE, ONE, sh, sl, ONE, 0, 0};
    u16 an[16] = {nhx,nhy,nhz, nlx,nly,nlz, nhx,nhy,nhz, 0,0,0,0,0,0,0};
    u16 bn[16] = {nhx,nhy,nhz, nhx,nhy,nhz, nlx,nly,nlz, 0,0,0,0,0,0,0};

    bf16x8* A8 = (bf16x8*)ws;            // A-record: frags [at0 at1 an0 an1] per point
    bf16x8* B8 = A8 + (size_t)NPTS*4;    // B-record: frags [bt0 bt1 bn0 bn1] per point
    bf16x8 v0, v1, v2, v3;
    #pragma unroll
    for (int k = 0; k < 8; ++k) { v0[k] = (short)at[k]; v1[k] = (short)at[k+8];
                                  v2[k] = (short)an[k]; v3[k] = (short)an[k+8]; }
    A8[(size_t)p*4+0] = v0; A8[(size_t)p*4+1] = v1; A8[(size_t)p*4+2] = v2; A8[(size_t)p*4+3] = v3;
    #pragma unroll
    for (int k = 0; k < 8; ++k) { v0[k] = (short)bt[k]; v1[k] = (short)bt[k+8];
                                  v2[k] = (short)bn[k]; v3[k] = (short)bn[k+8]; }
    B8[(size_t)p*4+0] = v0; B8[(size_t)p*4+1] = v1; B8[(size_t)p*4+2] = v2; B8[(size_t)p*4+3] = v3;
}

// Symmetric-pair kernel. R17 = R16 inner loop byte-for-byte (2 i-tiles/wave,
// depth-2 prefetch, (256,2), VGPR=64, zero spill) + NYG=25 geometry: grid
// 96x25 = 2400 blocks (g<24 -> 2 y's; g==24 -> y=48 alone). R16 post-mortem:
// instruction savings were canceled by occupancy crash 41->23% at 960 blocks;
// measured occupancy tracks GRID SIZE (2496->54%, 1920->48/41%, 1344->34%,
// 960->23%) much more than register count, and dur tracks occupancy at fixed
// VALU-inst count. This round tests that law with the lean inner loop: 2400
// blocks should restore ~45-50% occupancy on top of halved per-pair overhead.
// Accumulation order within (X,y,jt,gq,i-tile) unchanged -> bitwise-same energy.
// Wrapped map over 256-pt super-tiles: (I,J) = (X, (X+Y)%96); mult = 2 except
// Y==0 (diagonal, once) and Y==48 (hit from both ends) -> 96+96+96*47*2 = 96^2. ✓
__launch_bounds__(256, 2)
__global__ void energy_mfma(const u16* __restrict__ ws, float* __restrict__ out) {
    const int tid  = threadIdx.x;
    const int lane = tid & 63, wid = tid >> 6;
    const int half = lane >> 5, r32 = lane & 31;

    const int X  = blockIdx.x;                // 0..95 (super-tile row)
    const int g  = blockIdx.y;                // 0..24
    const int y0  = (g < 24) ? 2*g : 48;
    const int ycnt = (g < 24) ? 2 : 1;
    const int gi = X >> 5;                    // 32 super-tiles per segment

    const bf16x8* A8 = (const bf16x8*)ws;
    const bf16x8* B8 = A8 + (size_t)NPTS*4;

    // two persistent 32-row i-tiles per wave: rows pi and pi+128
    const int pi = X*256 + wid*32 + r32;
    const bf16x8 at0 = A8[pi*4 + half];
    const bf16x8 an0 = A8[pi*4 + 2 + half];
    const bf16x8 at1 = A8[pi*4 + 512 + half];        // +128 points * 4 frags
    const bf16x8 an1 = A8[pi*4 + 514 + half];

    f32x16 Z;
    #pragma unroll
    for (int k = 0; k < 16; ++k) Z[k] = 0.0f;

    const int lofs = r32*4 + half;            // per-lane frag offset within a j-tile

    // per-y addressing + weight (block-uniform), branchless (no indexed array)
    auto yinfo = [&](int y, int& vo, float& w) {
        int J = X + y; if (J >= NSUP) J -= NSUP;
        int jg = J >> 5;
        float base_w;
        if (gi == jg)                 base_w = (gi == 2) ? 2.0f : 1.8f;
        else if (gi == 2 || jg == 2)  base_w = -1.0f;
        else                          base_w = -0.8f;
        const float mult = (y == 0 || y == 48) ? 1.0f : 2.0f;
        w = base_w * mult;
        vo = J*1024 + lofs;                   // frag index: stride 4/point, 128/j-tile
    };

    // batched rcp: one v_rcp per 4 pairs; two independent partial chains
#define EPI(CT, CN, TS0, TS1) do {                                            \
        _Pragma("unroll")                                                     \
        for (int gq = 0; gq < 4; ++gq) {                                      \
            float t0 = CT[4*gq+0], t1 = CT[4*gq+1];                           \
            float t2 = CT[4*gq+2], t3 = CT[4*gq+3];                           \
            float q0 = t0*t0, q1 = t1*t1, q2 = t2*t2, q3 = t3*t3;             \
            float s01 = q0*q1, s23 = q2*q3;                                   \
            float r   = __builtin_amdgcn_rcpf(s01*s23);                       \
            float u   = __builtin_fmaf(CN[4*gq+1], q0, CN[4*gq+0]*q1);        \
            float v   = __builtin_fmaf(CN[4*gq+3], q2, CN[4*gq+2]*q3);        \
            float num = __builtin_fmaf(v, s01, u*s23);                        \
            if (gq & 1) TS1 = __builtin_fmaf(num, r, TS1);                    \
            else        TS0 = __builtin_fmaf(num, r, TS0);                    \
        }                                                                     \
    } while (0)

    float acc = 0.0f;
    int vo; float w;
    yinfo(y0, vo, w);

    // prologue: tiles 0 and 1 of the first y in flight (depth-2 pipeline)
    bf16x8 bt0 = B8[vo],       bn0 = B8[vo + 2];
    bf16x8 bt1 = B8[vo + 128], bn1 = B8[vo + 130];

    #pragma unroll 1
    for (int yy = 0; yy < ycnt; ++yy) {
        // next-y addressing (clamped on the last y -> harmless redundant loads)
        int von; float wn;
        yinfo((yy + 1 < ycnt) ? (y0 + yy + 1) : (y0 + yy), von, wn);

        float tsA0 = 0.0f, tsA1 = 0.0f;       // i-tile 0 partials
        float tsB0 = 0.0f, tsB1 = 0.0f;       // i-tile 1 partials
        #pragma unroll 2
        for (int jt = 0; jt < 8; ++jt) {
            // prefetch tile jt+2 (tiles 6/7 fetch next-y tiles 0/1)
            const int pofs = (jt < 6) ? (vo + (jt + 2)*128) : (von + (jt - 6)*128);
            bf16x8 pt = B8[pofs];
            bf16x8 pn = B8[pofs + 2];

            f32x16 ct, cn;
            ct = __builtin_amdgcn_mfma_f32_32x32x16_bf16(at0, bt0, Z, 0, 0, 0);
            cn = __builtin_amdgcn_mfma_f32_32x32x16_bf16(an0, bn0, Z, 0, 0, 0);
            EPI(ct, cn, tsA0, tsA1);
            ct = __builtin_amdgcn_mfma_f32_32x32x16_bf16(at1, bt0, Z, 0, 0, 0);
            cn = __builtin_amdgcn_mfma_f32_32x32x16_bf16(an1, bn0, Z, 0, 0, 0);
            EPI(ct, cn, tsB0, tsB1);

            // rotate pipeline (named registers; SSA renaming under unroll 2)
            bt0 = bt1; bn0 = bn1;
            bt1 = pt;  bn1 = pn;
        }
        acc = __builtin_fmaf(w, tsA0 + tsA1, acc);
        acc = __builtin_fmaf(w, tsB0 + tsB1, acc);
        vo = von; w = wn;
    }
#undef EPI

    // wave shuffle reduce -> 4 partials -> one atomic per block
    for (int off = 32; off; off >>= 1) acc += __shfl_down(acc, off, 64);
    __shared__ float partial[4];
    if ((tid & 63) == 0) partial[wid] = acc;
    __syncthreads();
    if (tid == 0)
        atomicAdd(out, (partial[0] + partial[1]) + (partial[2] + partial[3]));
}

extern "C" void kernel_launch(void* const* d_in, const int* in_sizes, int n_in,
                              void* d_out, int out_size, void* d_ws, size_t ws_size,
                              hipStream_t stream) {
    const float* sv = (const float*)d_in[0];
    const int*   si = (const int*)d_in[1];
    const float* tv = (const float*)d_in[2];
    const int*   ti = (const int*)d_in[3];
    const float* rn = (const float*)d_in[4];
    const float* rc = (const float*)d_in[5];
    float* out = (float*)d_out;
    u16*   ws  = (u16*)d_ws;                      // 2 x 24576 x 64 B = 3 MB features

    setup_feats<<<NPTS/256, 256, 0, stream>>>(sv, si, tv, ti, rn, rc, ws, out);
    dim3 grid(NXB, NYG);                          // 96 x 25 = 2400 blocks of 256
    energy_mfma<<<grid, 256, 0, stream>>>(ws, out);
}